// Round 19
// baseline (72.938 us; speedup 1.0000x reference)
//
#include <hip/hip_runtime.h>
#include <hip/hip_bf16.h>

// Problem constants
#define XH   64
#define XW   64
#define CIN  256
#define COUT 256
#define BATCH 4
#define KK9  9
#define M_TOT 16384      // BATCH*XH*XW
#define K_TOT 2304       // KK9*CIN
#define NKSTEP 36        // K_TOT/64
#define HKSTEP 18        // NKSTEP/2 (phase-1 K-split)

typedef __attribute__((ext_vector_type(8))) short short8;
typedef __attribute__((ext_vector_type(4))) short short4v;
typedef __attribute__((ext_vector_type(4))) float f32x4;

// Workspace layout (bytes)
#define XT_OFF   0
#define XT_BYTES (BATCH*4096*CIN*2)           // 8,388,608 (bf16)
#define WT_OFF   (XT_OFF + XT_BYTES)
#define WT_BYTES (COUT*K_TOT*2)               // 1,179,648  Wt3: A-fragment-ordered (k0)
#define WOT_OFF  (WT_OFF + WT_BYTES)
#define WOT_BYTES (36*2*2*64*8*2)             // 147,456    Wot3: A-fragment-ordered (k0b)

__device__ __forceinline__ float b2f(short s) {
  union { float f; unsigned u; } x;
  x.u = ((unsigned)(unsigned short)s) << 16;
  return x.f;
}

struct Taps4 { short4v t00, t01, t10, t11; };

// ---------------------------------------------------------------------------
// K0: w_conv (O,C,3,3) f32 -> Wt3 bf16, per-lane A-fragment order:
// Wt3[tk(36)][og(16)][kc(2)][lane(64)][j(8)]
// ---------------------------------------------------------------------------
__global__ __launch_bounds__(256) void k0_wt(const float* __restrict__ wconv,
                                             __hip_bfloat16* __restrict__ Wt3) {
  int e = blockIdx.x * 256 + threadIdx.x;      // < 589824
  int j3   = e & 7;
  int lane = (e >> 3) & 63;
  int kc   = (e >> 9) & 1;
  int og   = (e >> 10) & 15;
  int tk   = e >> 14;
  int o = og * 16 + (lane & 15);
  int k = tk * 64 + kc * 32 + ((lane >> 4) << 3) + j3;
  int kk = k >> 8, c = k & 255;
  float v = wconv[(o * CIN + c) * KK9 + kk];
  Wt3[e] = __float2bfloat16(v);
}

// ---------------------------------------------------------------------------
// K0b: w_off -> Wot3 bf16, A-fragment order:
// Wot3[tk(36)][wc(2)][kc(2)][lane(64)][j(8)]  (oc >= 27 zero-padded)
// ---------------------------------------------------------------------------
__global__ __launch_bounds__(256) void k0b_wot(const float* __restrict__ woff,
                                               __hip_bfloat16* __restrict__ Wot3) {
  int e = blockIdx.x * 256 + threadIdx.x;      // < 73728
  int j3   = e & 7;
  int lane = (e >> 3) & 63;
  int kc   = (e >> 9) & 1;
  int wc   = (e >> 10) & 1;
  int tk   = e >> 11;
  int oc = wc * 16 + (lane & 15);
  int k = tk * 64 + kc * 32 + ((lane >> 4) << 3) + j3;
  int kk = k >> 8, c = k & 255;
  float v = (oc < 27) ? woff[((size_t)(oc * 256 + c)) * 9 + kk] : 0.f;
  Wot3[e] = __float2bfloat16(v);
}

// ---------------------------------------------------------------------------
// KT: transpose x (B,C,H,W) f32 -> xTh[b][hw][c] bf16
// ---------------------------------------------------------------------------
__global__ __launch_bounds__(256) void kt_xt(const float* __restrict__ x,
                                             __hip_bfloat16* __restrict__ xTh) {
  __shared__ float t[64][65];
  int blk = blockIdx.x;
  int hwg = blk & 63;
  int cg  = (blk >> 6) & 3;
  int b   = blk >> 8;
  int hw0 = hwg * 64, c0 = cg * 64;
  int l = threadIdx.x & 63, q = threadIdx.x >> 6;
  const float* xb = x + ((size_t)(b * 256 + c0) << 12) + hw0;
#pragma unroll
  for (int i = 0; i < 16; ++i) {
    int cl = q * 16 + i;
    t[cl][l] = xb[((size_t)cl << 12) + l];
  }
  __syncthreads();
  __hip_bfloat16* xTb = xTh + (((size_t)b << 12) + hw0) * 256 + c0;
#pragma unroll
  for (int i = 0; i < 16; ++i) {
    int hwl = q * 16 + i;
    xTb[(size_t)hwl * 256 + l] = __float2bfloat16(t[l][hwl]);
  }
}

// ---------------------------------------------------------------------------
// K23: fully fused. 32 m x 256 o per block, grid 512, 512 thr (8 waves)
// -> 2 blocks/CU x 8 waves = 16 waves/CU = 4 waves/SIMD (2x R14's TLP; the
// one untried lever after R11-R17 schedule fixes all nulled at 2/SIMD).
// Phase-1: offset-conv GEMM, K split across 2 wave-groups (18 steps each),
//   partials in sOMp[2], summed (+bias) when building gather params.
// Phase-2: R14-proven shape at 8 waves: wave owns 32o; W-frags direct from
//   Wt3 (L2) double-buffered in regs; taps reg-staged; sV dbuf in LDS;
//   one barrier per K-step.
// ---------------------------------------------------------------------------
__global__ __launch_bounds__(512, 4) void k23_fused(const __hip_bfloat16* __restrict__ xTh,
                                                    const __hip_bfloat16* __restrict__ Wt3,
                                                    const __hip_bfloat16* __restrict__ Wot3,
                                                    const float* __restrict__ boff,
                                                    float* __restrict__ out) {
  __shared__ __align__(16) __hip_bfloat16 sPV[2][32 * 64];   // 8 KB (ph1: per-group patch; ph2: V dbuf)
  __shared__ float sOMp[2][32][33];                           // 8.25 KB partials (padded)
  __shared__ float sw00[288], sw01[288], sw10[288], sw11[288];
  __shared__ int   so00[288], so01[288], so10[288], so11[288];

  int bid = blockIdx.x;
  int tm = ((bid & 7) << 6) | (bid >> 3);   // chunked XCD swizzle, 0..511
  int tid = threadIdx.x;
  int wv = tid >> 6, lane = tid & 63;
  int lo = lane & 15, hi = lane >> 4;
  int b = tm >> 7;
  int m0 = tm * 32;

  // ===================== PHASE 1: om partials (K-split) =====================
  {
    int g  = wv >> 2;                 // K-group 0/1
    int wq = wv & 3;
    int wr = wq >> 1, wc = wq & 1;    // 16m x 16oc quadrant
    int gt = tid & 255;               // tid within group
    int prow = gt >> 3;               // 0..31
    int pkb  = (gt & 7) * 8;          // 0..56
    int pcolz = pkb ^ ((prow & 7) << 3);
    int m_s = m0 + prow;
    int hw_s = m_s & 4095, h_s = hw_s >> 6, w_s = hw_s & 63;

    f32x4 acc1 = {0.f, 0.f, 0.f, 0.f};
    for (int s = 0; s < HKSTEP; ++s) {
      int tk = g * HKSTEP + s;
      // stage patch(tk) for this group's buffer
      int kk = tk >> 2, cc = tk & 3;
      int ky = kk / 3, kx = kk - ky * 3;
      int yy = h_s + ky - 1, xx = w_s + kx - 1;
      short8 h8 = {0, 0, 0, 0, 0, 0, 0, 0};
      if (((unsigned)yy < 64u) && ((unsigned)xx < 64u))
        h8 = *(const short8*)(xTh + ((((size_t)b << 12) + yy * 64 + xx) << 8) + cc * 64 + pkb);
      *(short8*)&sPV[g][prow * 64 + pcolz] = h8;
      __syncthreads();
#pragma unroll
      for (int kc = 0; kc < 2; ++kc) {
        int cz = (kc * 32 + hi * 8) ^ ((lo & 7) << 3);
        short8 bfr = *(const short8*)&sPV[g][(wr * 16 + lo) * 64 + cz];
        short8 a = *(const short8*)((const char*)Wot3
                    + ((((size_t)tk * 2 + wc) * 2 + kc) << 10) + lane * 16);
        acc1 = __builtin_amdgcn_mfma_f32_16x16x32_bf16(a, bfr, acc1, 0, 0, 0);
      }
      __syncthreads();
    }
    // partial epilogue: C layout col=lo -> m, row=hi*4+r -> oc
    int oc0 = wc * 16 + hi * 4;
#pragma unroll
    for (int r = 0; r < 4; ++r)
      sOMp[g][wr * 16 + lo][oc0 + r] = acc1[r];
  }
  __syncthreads();   // both partials complete

  // ============== PHASE 2 prologue A: gather params (sum partials) ==========
  for (int it = tid; it < 288; it += 512) {
    int kk = it >> 5, row = it & 31;
    int m = m0 + row;
    int hw = m & 4095, h = hw >> 6, w = hw & 63;
    float dy = sOMp[0][row][2 * kk]     + sOMp[1][row][2 * kk]     + boff[2 * kk];
    float dx = sOMp[0][row][2 * kk + 1] + sOMp[1][row][2 * kk + 1] + boff[2 * kk + 1];
    float mz = sOMp[0][row][18 + kk]    + sOMp[1][row][18 + kk]    + boff[18 + kk];
    int ky = kk / 3, kx = kk - ky * 3;
    float py = dy + (float)(h - 1 + ky);
    float px = dx + (float)(w - 1 + kx);
    float y0f = floorf(py), x0f = floorf(px);
    float wy = py - y0f, wx = px - x0f;
    int y0 = (int)y0f, x0 = (int)x0f;
    bool vy0 = (unsigned)y0 < 64u, vy1 = (unsigned)(y0 + 1) < 64u;
    bool vx0 = (unsigned)x0 < 64u, vx1 = (unsigned)(x0 + 1) < 64u;
    int cy0 = min(max(y0, 0), 63), cy1 = min(max(y0 + 1, 0), 63);
    int cx0 = min(max(x0, 0), 63), cx1 = min(max(x0 + 1, 0), 63);
    float mask = 1.f / (1.f + __expf(-mz));
    sw00[it] = (vy0 && vx0) ? (1.f - wy) * (1.f - wx) * mask : 0.f;
    sw01[it] = (vy0 && vx1) ? (1.f - wy) * wx * mask : 0.f;
    sw10[it] = (vy1 && vx0) ? wy * (1.f - wx) * mask : 0.f;
    sw11[it] = (vy1 && vx1) ? wy * wx * mask : 0.f;
    so00[it] = cy0 * 64 + cx0;
    so01[it] = cy0 * 64 + cx1;
    so10[it] = cy1 * 64 + cx0;
    so11[it] = cy1 * 64 + cx1;
  }
  __syncthreads();   // params visible

  // ===================== PHASE 2: main GEMM (8 waves) =====================
  const __hip_bfloat16* xb = xTh + ((size_t)b << 20);
  int vrow = tid >> 4;          // 0..31 (16 threads/row, 4 ch each)
  int chq  = tid & 15;
  int colz = (chq * 4) ^ ((vrow & 7) << 3);

  auto loadTaps = [&](int tkq, Taps4& T) {
    int it = (tkq >> 2) * 32 + vrow;
    const __hip_bfloat16* base = xb + (tkq & 3) * 64 + chq * 4;
    T.t00 = *(const short4v*)(base + (size_t)so00[it] * 256);
    T.t01 = *(const short4v*)(base + (size_t)so01[it] * 256);
    T.t10 = *(const short4v*)(base + (size_t)so10[it] * 256);
    T.t11 = *(const short4v*)(base + (size_t)so11[it] * 256);
  };
  auto buildV = [&](int tkq, const Taps4& T, int buf) {
    int it = (tkq >> 2) * 32 + vrow;
    float a00 = sw00[it], a01 = sw01[it], a10 = sw10[it], a11 = sw11[it];
    __hip_bfloat16 h4[4];
#pragma unroll
    for (int j = 0; j < 4; ++j) {
      float v = a00 * b2f(T.t00[j]) + a01 * b2f(T.t01[j])
              + a10 * b2f(T.t10[j]) + a11 * b2f(T.t11[j]);
      h4[j] = __float2bfloat16(v);
    }
    *(short4v*)&sPV[buf][vrow * 64 + colz] = *(const short4v*)h4;
  };
  // A-frags: wave owns o in [wv*32, wv*32+32) -> og = wv*2+fo
  auto loadW = [&](int tkq, short8 (&aw)[4]) {
#pragma unroll
    for (int fo = 0; fo < 2; ++fo)
#pragma unroll
      for (int kc = 0; kc < 2; ++kc)
        aw[fo * 2 + kc] = *(const short8*)((const char*)Wt3
                          + ((((size_t)tkq * 16 + (wv * 2 + fo)) * 2 + kc) << 10)
                          + lane * 16);
  };

  f32x4 zero4 = {0.f, 0.f, 0.f, 0.f};
  f32x4 acc[2][2];
#pragma unroll
  for (int fo = 0; fo < 2; ++fo)
#pragma unroll
    for (int fm = 0; fm < 2; ++fm) acc[fo][fm] = zero4;

  Taps4 TA, TB;
  short8 awA[4], awB[4];
  loadW(0, awA);
  loadTaps(0, TA);
  buildV(0, TA, 0);
  loadTaps(1, TB);
  asm volatile("s_waitcnt lgkmcnt(0)" ::: "memory");
  __builtin_amdgcn_s_barrier();

  auto body = [&](int tk, Taps4& Tuse, Taps4& Tload,
                  short8 (&awUse)[4], short8 (&awLoad)[4]) {
    int cb = tk & 1, nb = cb ^ 1;
    int tk1 = min(tk + 1, NKSTEP - 1), tk2 = min(tk + 2, NKSTEP - 1);
    loadW(tk1, awLoad);
    loadTaps(tk2, Tload);
    __builtin_amdgcn_sched_barrier(0);
    buildV(tk1, Tuse, nb);

    __builtin_amdgcn_s_setprio(1);
#pragma unroll
    for (int kc = 0; kc < 2; ++kc) {
      int cz = (kc * 32 + hi * 8) ^ ((lo & 7) << 3);
      short8 bv[2];
#pragma unroll
      for (int fm = 0; fm < 2; ++fm)
        bv[fm] = *(const short8*)&sPV[cb][(fm * 16 + lo) * 64 + cz];
#pragma unroll
      for (int fo = 0; fo < 2; ++fo)
#pragma unroll
        for (int fm = 0; fm < 2; ++fm)
          acc[fo][fm] = __builtin_amdgcn_mfma_f32_16x16x32_bf16(awUse[fo * 2 + kc], bv[fm], acc[fo][fm], 0, 0, 0);
    }
    __builtin_amdgcn_s_setprio(0);

    if (tk + 1 < NKSTEP) {
      asm volatile("s_waitcnt lgkmcnt(0)" ::: "memory");
      __builtin_amdgcn_s_barrier();
    }
  };

  for (int tkp = 0; tkp < NKSTEP; tkp += 2) {
    body(tkp,     TB, TA, awA, awB);
    body(tkp + 1, TA, TB, awB, awA);
  }

  // epilogue: C layout col = lane&15 -> m, row = hi*4+r -> o
  int hwbase = m0 & 4095;
#pragma unroll
  for (int fo = 0; fo < 2; ++fo) {
    int o = wv * 32 + fo * 16 + hi * 4;
#pragma unroll
    for (int fm = 0; fm < 2; ++fm) {
      int mloc = hwbase + fm * 16 + lo;
#pragma unroll
      for (int r = 0; r < 4; ++r)
        out[((size_t)(b * 256 + o + r)) * 4096 + mloc] = acc[fo][fm][r];
    }
  }
}

// ---------------------------------------------------------------------------
extern "C" void kernel_launch(void* const* d_in, const int* in_sizes, int n_in,
                              void* d_out, int out_size, void* d_ws, size_t ws_size,
                              hipStream_t stream) {
  (void)in_sizes; (void)n_in; (void)out_size; (void)ws_size;
  const float* x     = (const float*)d_in[0];
  const float* woff  = (const float*)d_in[1];
  const float* boff  = (const float*)d_in[2];
  const float* wconv = (const float*)d_in[3];
  char* ws = (char*)d_ws;
  __hip_bfloat16* xTh  = (__hip_bfloat16*)(ws + XT_OFF);
  __hip_bfloat16* Wt3  = (__hip_bfloat16*)(ws + WT_OFF);
  __hip_bfloat16* Wot3 = (__hip_bfloat16*)(ws + WOT_OFF);
  float* out = (float*)d_out;

  hipLaunchKernelGGL(k0_wt,     dim3(2304), dim3(256), 0, stream, wconv, Wt3);
  hipLaunchKernelGGL(k0b_wot,   dim3(288),  dim3(256), 0, stream, woff, Wot3);
  hipLaunchKernelGGL(kt_xt,     dim3(1024), dim3(256), 0, stream, x, xTh);
  hipLaunchKernelGGL(k23_fused, dim3(512),  dim3(512), 0, stream, xTh, Wt3, Wot3, boff, out);
}

// Round 20
// 67.988 us; speedup vs baseline: 1.0728x; 1.0728x over previous
//
#include <hip/hip_runtime.h>
#include <hip/hip_bf16.h>

// Problem constants
#define XH   64
#define XW   64
#define CIN  256
#define COUT 256
#define BATCH 4
#define KK9  9
#define M_TOT 16384      // BATCH*XH*XW
#define K_TOT 2304       // KK9*CIN
#define NKSTEP 36        // K_TOT/64

typedef __attribute__((ext_vector_type(8))) short short8;
typedef __attribute__((ext_vector_type(4))) float f32x4;

// Workspace layout (bytes)
#define XT_OFF   0
#define XT_BYTES (BATCH*4096*CIN*2)           // 8,388,608 (bf16)
#define WT_OFF   (XT_OFF + XT_BYTES)
#define WT_BYTES (COUT*K_TOT*2)               // 1,179,648  Wt3: A-fragment-ordered (k0)
#define WOT_OFF  (WT_OFF + WT_BYTES)
#define WOT_BYTES (36*2*2*64*8*2)             // 147,456    Wot3: A-fragment-ordered (k0b)

__device__ __forceinline__ float b2f(short s) {
  union { float f; unsigned u; } x;
  x.u = ((unsigned)(unsigned short)s) << 16;
  return x.f;
}

struct Taps { short8 t00, t01, t10, t11; };

// ---------------------------------------------------------------------------
// K0: w_conv (O,C,3,3) f32 -> Wt3 bf16, per-lane A-fragment order:
// Wt3[tk(36)][og(16)][kc(2)][lane(64)][j(8)]
// ---------------------------------------------------------------------------
__global__ __launch_bounds__(256) void k0_wt(const float* __restrict__ wconv,
                                             __hip_bfloat16* __restrict__ Wt3) {
  int e = blockIdx.x * 256 + threadIdx.x;      // < 589824
  int j3   = e & 7;
  int lane = (e >> 3) & 63;
  int kc   = (e >> 9) & 1;
  int og   = (e >> 10) & 15;
  int tk   = e >> 14;
  int o = og * 16 + (lane & 15);
  int k = tk * 64 + kc * 32 + ((lane >> 4) << 3) + j3;
  int kk = k >> 8, c = k & 255;
  float v = wconv[(o * CIN + c) * KK9 + kk];
  Wt3[e] = __float2bfloat16(v);
}

// ---------------------------------------------------------------------------
// K0b: w_off -> Wot3 bf16, A-fragment order:
// Wot3[tk(36)][wc(2)][kc(2)][lane(64)][j(8)]  (oc >= 27 zero-padded)
// ---------------------------------------------------------------------------
__global__ __launch_bounds__(256) void k0b_wot(const float* __restrict__ woff,
                                               __hip_bfloat16* __restrict__ Wot3) {
  int e = blockIdx.x * 256 + threadIdx.x;      // < 73728
  int j3   = e & 7;
  int lane = (e >> 3) & 63;
  int kc   = (e >> 9) & 1;
  int wc   = (e >> 10) & 1;
  int tk   = e >> 11;
  int oc = wc * 16 + (lane & 15);
  int k = tk * 64 + kc * 32 + ((lane >> 4) << 3) + j3;
  int kk = k >> 8, c = k & 255;
  float v = (oc < 27) ? woff[((size_t)(oc * 256 + c)) * 9 + kk] : 0.f;
  Wot3[e] = __float2bfloat16(v);
}

// ---------------------------------------------------------------------------
// KT: transpose x (B,C,H,W) f32 -> xTh[b][hw][c] bf16
// ---------------------------------------------------------------------------
__global__ __launch_bounds__(256) void kt_xt(const float* __restrict__ x,
                                             __hip_bfloat16* __restrict__ xTh) {
  __shared__ float t[64][65];
  int blk = blockIdx.x;
  int hwg = blk & 63;
  int cg  = (blk >> 6) & 3;
  int b   = blk >> 8;
  int hw0 = hwg * 64, c0 = cg * 64;
  int l = threadIdx.x & 63, q = threadIdx.x >> 6;
  const float* xb = x + ((size_t)(b * 256 + c0) << 12) + hw0;
#pragma unroll
  for (int i = 0; i < 16; ++i) {
    int cl = q * 16 + i;
    t[cl][l] = xb[((size_t)cl << 12) + l];
  }
  __syncthreads();
  __hip_bfloat16* xTb = xTh + (((size_t)b << 12) + hw0) * 256 + c0;
#pragma unroll
  for (int i = 0; i < 16; ++i) {
    int hwl = q * 16 + i;
    xTb[(size_t)hwl * 256 + l] = __float2bfloat16(t[l][hwl]);
  }
}

// ---------------------------------------------------------------------------
// K23: FULLY fused. 32 m x 256 o per block, grid 512 (2 blocks/CU), 256 thr
// (4 waves). Identical to R15 (best measured) EXCEPT phase-1 is kk-STAGED:
// stage the 32-row x 256-ch patch once per kk (16 KB, 4 XOR-swizzled
// sub-tiles), then 4 cc-steps of MFMA from LDS. Barriers 72 -> 18,
// staging issues 36 -> 9. sPatch aliases phase-2's sPV dbuf (16 KB union).
// ---------------------------------------------------------------------------
__global__ __launch_bounds__(256, 2) void k23_fused(const __hip_bfloat16* __restrict__ xTh,
                                                    const __hip_bfloat16* __restrict__ Wt3,
                                                    const __hip_bfloat16* __restrict__ Wot3,
                                                    const float* __restrict__ boff,
                                                    float* __restrict__ out) {
  __shared__ __align__(16) __hip_bfloat16 sPatch[4][32 * 64];  // 16 KB (ph1: 4 cc sub-tiles; ph2: sPV dbuf = first 8 KB)
  __shared__ float sOM[32][33];                                 // padded: conflict-free
  __shared__ float sw00[288], sw01[288], sw10[288], sw11[288];
  __shared__ int   so00[288], so01[288], so10[288], so11[288];

  __hip_bfloat16 (*sPV)[32 * 64] = sPatch;   // alias: sPV[0/1] = sPatch[0/1]

  int bid = blockIdx.x;
  int tm = ((bid & 7) << 6) | (bid >> 3);   // chunked XCD swizzle, 0..511
  int tid = threadIdx.x;
  int wv = tid >> 6, lane = tid & 63;
  int lo = lane & 15, hi = lane >> 4;
  int b = tm >> 7;
  int m0 = tm * 32;

  // ===================== PHASE 1: om for own 32 rows (kk-staged) ==========
  {
    int wr = wv >> 1, wc = wv & 1;
    int prow = tid >> 3;            // 0..31
    int pkb  = (tid & 7) * 8;       // 0..56
    int pcolz = pkb ^ ((prow & 7) << 3);
    int m_s = m0 + prow;
    int hw_s = m_s & 4095, h_s = hw_s >> 6, w_s = hw_s & 63;

    f32x4 acc1 = {0.f, 0.f, 0.f, 0.f};
    const short8 zero8 = {0,0,0,0,0,0,0,0};

    for (int kk = 0; kk < KK9; ++kk) {
      int ky = kk / 3, kx = kk - ky * 3;
      int yy = h_s + ky - 1, xx = w_s + kx - 1;
      bool valid = ((unsigned)yy < 64u) && ((unsigned)xx < 64u);
      int cy = min(max(yy, 0), 63), cx = min(max(xx, 0), 63);
      const __hip_bfloat16* src = xTh + ((((size_t)b << 12) + cy * 64 + cx) << 8) + pkb;
      // stage all 4 cc sub-tiles for this kk (64 B/thread)
#pragma unroll
      for (int cc = 0; cc < 4; ++cc) {
        short8 h8 = valid ? *(const short8*)(src + cc * 64) : zero8;
        *(short8*)&sPatch[cc][prow * 64 + pcolz] = h8;
      }
      __syncthreads();
      // 4 cc-steps (8 MFMA/wave) from LDS; Wot3 frags direct from L2
#pragma unroll
      for (int cc = 0; cc < 4; ++cc) {
        int tk = kk * 4 + cc;
#pragma unroll
        for (int kc = 0; kc < 2; ++kc) {
          int cz = (kc * 32 + hi * 8) ^ ((lo & 7) << 3);
          short8 bfr = *(const short8*)&sPatch[cc][(wr * 16 + lo) * 64 + cz];
          short8 a = *(const short8*)((const char*)Wot3
                      + ((((size_t)tk * 2 + wc) * 2 + kc) << 10) + lane * 16);
          acc1 = __builtin_amdgcn_mfma_f32_16x16x32_bf16(a, bfr, acc1, 0, 0, 0);
        }
      }
      __syncthreads();
    }

    int oc0 = wc * 16 + hi * 4;
#pragma unroll
    for (int r = 0; r < 4; ++r) {
      float bias = (oc0 + r < 27) ? boff[oc0 + r] : 0.f;
      sOM[wr * 16 + lo][oc0 + r] = acc1[r] + bias;
    }
  }
  __syncthreads();   // sOM complete

  // ============== PHASE 2 prologue A: gather params from sOM ==============
  for (int it = tid; it < 288; it += 256) {
    int kk = it >> 5, row = it & 31;
    int m = m0 + row;
    int hw = m & 4095, h = hw >> 6, w = hw & 63;
    float dy = sOM[row][2 * kk];
    float dx = sOM[row][2 * kk + 1];
    float mz = sOM[row][18 + kk];
    int ky = kk / 3, kx = kk - ky * 3;
    float py = dy + (float)(h - 1 + ky);
    float px = dx + (float)(w - 1 + kx);
    float y0f = floorf(py), x0f = floorf(px);
    float wy = py - y0f, wx = px - x0f;
    int y0 = (int)y0f, x0 = (int)x0f;
    bool vy0 = (unsigned)y0 < 64u, vy1 = (unsigned)(y0 + 1) < 64u;
    bool vx0 = (unsigned)x0 < 64u, vx1 = (unsigned)(x0 + 1) < 64u;
    int cy0 = min(max(y0, 0), 63), cy1 = min(max(y0 + 1, 0), 63);
    int cx0 = min(max(x0, 0), 63), cx1 = min(max(x0 + 1, 0), 63);
    float mask = 1.f / (1.f + __expf(-mz));
    sw00[it] = (vy0 && vx0) ? (1.f - wy) * (1.f - wx) * mask : 0.f;
    sw01[it] = (vy0 && vx1) ? (1.f - wy) * wx * mask : 0.f;
    sw10[it] = (vy1 && vx0) ? wy * (1.f - wx) * mask : 0.f;
    sw11[it] = (vy1 && vx1) ? wy * wx * mask : 0.f;
    so00[it] = cy0 * 64 + cx0;
    so01[it] = cy0 * 64 + cx1;
    so10[it] = cy1 * 64 + cx0;
    so11[it] = cy1 * 64 + cx1;
  }
  __syncthreads();   // params visible

  // ===================== PHASE 2: main GEMM (R15/R14 body) =================
  const __hip_bfloat16* xb = xTh + ((size_t)b << 20);
  int vrow = tid >> 3;          // 0..31 (8 threads/row, 8 ch each)
  int chq  = tid & 7;
  int colz = (chq * 8) ^ ((vrow & 7) << 3);

  auto loadTaps = [&](int tkq, Taps& T) {
    int it = (tkq >> 2) * 32 + vrow;
    const __hip_bfloat16* base = xb + (tkq & 3) * 64 + chq * 8;
    T.t00 = *(const short8*)(base + (size_t)so00[it] * 256);
    T.t01 = *(const short8*)(base + (size_t)so01[it] * 256);
    T.t10 = *(const short8*)(base + (size_t)so10[it] * 256);
    T.t11 = *(const short8*)(base + (size_t)so11[it] * 256);
  };
  auto buildV = [&](int tkq, const Taps& T, int buf) {
    int it = (tkq >> 2) * 32 + vrow;
    float a00 = sw00[it], a01 = sw01[it], a10 = sw10[it], a11 = sw11[it];
    __hip_bfloat16 h8[8];
#pragma unroll
    for (int j = 0; j < 8; ++j) {
      float v = a00 * b2f(T.t00[j]) + a01 * b2f(T.t01[j])
              + a10 * b2f(T.t10[j]) + a11 * b2f(T.t11[j]);
      h8[j] = __float2bfloat16(v);
    }
    *(short8*)&sPV[buf][vrow * 64 + colz] = *(const short8*)h8;
  };
  // A-frags: wave wv owns o in [wv*64, wv*64+64) -> og = wv*4+fo
  auto loadW = [&](int tkq, short8 (&aw)[8]) {
#pragma unroll
    for (int fo = 0; fo < 4; ++fo)
#pragma unroll
      for (int kc = 0; kc < 2; ++kc)
        aw[fo * 2 + kc] = *(const short8*)((const char*)Wt3
                          + ((((size_t)tkq * 16 + (wv * 4 + fo)) * 2 + kc) << 10)
                          + lane * 16);
  };

  f32x4 zero4 = {0.f, 0.f, 0.f, 0.f};
  f32x4 acc[4][2];
#pragma unroll
  for (int fo = 0; fo < 4; ++fo)
#pragma unroll
    for (int fm = 0; fm < 2; ++fm) acc[fo][fm] = zero4;

  Taps TA, TB;
  short8 awA[8], awB[8];
  loadW(0, awA);
  loadTaps(0, TA);
  buildV(0, TA, 0);
  loadTaps(1, TB);
  asm volatile("s_waitcnt lgkmcnt(0)" ::: "memory");
  __builtin_amdgcn_s_barrier();

  auto body = [&](int tk, Taps& Tuse, Taps& Tload,
                  short8 (&awUse)[8], short8 (&awLoad)[8]) {
    int cb = tk & 1, nb = cb ^ 1;
    int tk1 = min(tk + 1, NKSTEP - 1), tk2 = min(tk + 2, NKSTEP - 1);
    loadW(tk1, awLoad);
    loadTaps(tk2, Tload);
    __builtin_amdgcn_sched_barrier(0);
    buildV(tk1, Tuse, nb);

    __builtin_amdgcn_s_setprio(1);
#pragma unroll
    for (int kc = 0; kc < 2; ++kc) {
      int cz = (kc * 32 + hi * 8) ^ ((lo & 7) << 3);
      short8 bv[2];
#pragma unroll
      for (int fm = 0; fm < 2; ++fm)
        bv[fm] = *(const short8*)&sPV[cb][(fm * 16 + lo) * 64 + cz];
#pragma unroll
      for (int fo = 0; fo < 4; ++fo)
#pragma unroll
        for (int fm = 0; fm < 2; ++fm)
          acc[fo][fm] = __builtin_amdgcn_mfma_f32_16x16x32_bf16(awUse[fo * 2 + kc], bv[fm], acc[fo][fm], 0, 0, 0);
    }
    __builtin_amdgcn_s_setprio(0);

    if (tk + 1 < NKSTEP) {
      asm volatile("s_waitcnt lgkmcnt(0)" ::: "memory");
      __builtin_amdgcn_s_barrier();
    }
  };

  for (int tkp = 0; tkp < NKSTEP; tkp += 2) {
    body(tkp,     TB, TA, awA, awB);
    body(tkp + 1, TA, TB, awB, awA);
  }

  // epilogue: C layout col = lane&15 -> m, row = hi*4+r -> o
  int hwbase = m0 & 4095;
#pragma unroll
  for (int fo = 0; fo < 4; ++fo) {
    int o = wv * 64 + fo * 16 + hi * 4;
#pragma unroll
    for (int fm = 0; fm < 2; ++fm) {
      int mloc = hwbase + fm * 16 + lo;
#pragma unroll
      for (int r = 0; r < 4; ++r)
        out[((size_t)(b * 256 + o + r)) * 4096 + mloc] = acc[fo][fm][r];
    }
  }
}

// ---------------------------------------------------------------------------
extern "C" void kernel_launch(void* const* d_in, const int* in_sizes, int n_in,
                              void* d_out, int out_size, void* d_ws, size_t ws_size,
                              hipStream_t stream) {
  (void)in_sizes; (void)n_in; (void)out_size; (void)ws_size;
  const float* x     = (const float*)d_in[0];
  const float* woff  = (const float*)d_in[1];
  const float* boff  = (const float*)d_in[2];
  const float* wconv = (const float*)d_in[3];
  char* ws = (char*)d_ws;
  __hip_bfloat16* xTh  = (__hip_bfloat16*)(ws + XT_OFF);
  __hip_bfloat16* Wt3  = (__hip_bfloat16*)(ws + WT_OFF);
  __hip_bfloat16* Wot3 = (__hip_bfloat16*)(ws + WOT_OFF);
  float* out = (float*)d_out;

  hipLaunchKernelGGL(k0_wt,     dim3(2304), dim3(256), 0, stream, wconv, Wt3);
  hipLaunchKernelGGL(k0b_wot,   dim3(288),  dim3(256), 0, stream, woff, Wot3);
  hipLaunchKernelGGL(kt_xt,     dim3(1024), dim3(256), 0, stream, x, xTh);
  hipLaunchKernelGGL(k23_fused, dim3(512),  dim3(256), 0, stream, xTh, Wt3, Wot3, boff, out);
}

// Round 21
// 61.775 us; speedup vs baseline: 1.1807x; 1.1006x over previous
//
#include <hip/hip_runtime.h>
#include <hip/hip_bf16.h>

// Problem constants
#define XH   64
#define XW   64
#define CIN  256
#define COUT 256
#define BATCH 4
#define KK9  9
#define M_TOT 16384      // BATCH*XH*XW
#define K_TOT 2304       // KK9*CIN
#define NKSTEP 36        // K_TOT/64

typedef __attribute__((ext_vector_type(8))) short short8;
typedef __attribute__((ext_vector_type(4))) float f32x4;

// Workspace layout (bytes)
#define XT_OFF   0
#define XT_BYTES (BATCH*4096*CIN*2)           // 8,388,608 (bf16)
#define WT_OFF   (XT_OFF + XT_BYTES)
#define WT_BYTES (COUT*K_TOT*2)               // 1,179,648  Wt3: A-fragment-ordered
#define WOT_OFF  (WT_OFF + WT_BYTES)
#define WOT_BYTES (36*2*2*64*8*2)             // 147,456    Wot3: A-fragment-ordered

__device__ __forceinline__ float b2f(short s) {
  union { float f; unsigned u; } x;
  x.u = ((unsigned)(unsigned short)s) << 16;
  return x.f;
}

struct Taps { short8 t00, t01, t10, t11; };

// ---------------------------------------------------------------------------
// K_PREP: merged k0 + k0b + kt (mutually independent; one dispatch removes
// two kernel-boundary gaps ~3 us each and runs them concurrently).
// blocks [0,2304)      : Wt3  (w_conv -> A-fragment order)
// blocks [2304,2592)   : Wot3 (w_off  -> A-fragment order, oc>=27 padded)
// blocks [2592,3616)   : xTh  (transpose x -> [b][hw][c] bf16)
// ---------------------------------------------------------------------------
__global__ __launch_bounds__(256) void k_prep(const float* __restrict__ x,
                                              const float* __restrict__ woff,
                                              const float* __restrict__ wconv,
                                              __hip_bfloat16* __restrict__ Wt3,
                                              __hip_bfloat16* __restrict__ Wot3,
                                              __hip_bfloat16* __restrict__ xTh) {
  int blk = blockIdx.x;
  if (blk < 2304) {
    // ---- k0: Wt3[tk(36)][og(16)][kc(2)][lane(64)][j(8)] ----
    int e = blk * 256 + threadIdx.x;           // < 589824
    int j3   = e & 7;
    int lane = (e >> 3) & 63;
    int kc   = (e >> 9) & 1;
    int og   = (e >> 10) & 15;
    int tk   = e >> 14;
    int o = og * 16 + (lane & 15);
    int k = tk * 64 + kc * 32 + ((lane >> 4) << 3) + j3;
    int kk = k >> 8, c = k & 255;
    float v = wconv[(o * CIN + c) * KK9 + kk];
    Wt3[e] = __float2bfloat16(v);
  } else if (blk < 2592) {
    // ---- k0b: Wot3[tk(36)][wc(2)][kc(2)][lane(64)][j(8)] ----
    int e = (blk - 2304) * 256 + threadIdx.x;  // < 73728
    int j3   = e & 7;
    int lane = (e >> 3) & 63;
    int kc   = (e >> 9) & 1;
    int wc   = (e >> 10) & 1;
    int tk   = e >> 11;
    int oc = wc * 16 + (lane & 15);
    int k = tk * 64 + kc * 32 + ((lane >> 4) << 3) + j3;
    int kk = k >> 8, c = k & 255;
    float v = (oc < 27) ? woff[((size_t)(oc * 256 + c)) * 9 + kk] : 0.f;
    Wot3[e] = __float2bfloat16(v);
  } else {
    // ---- kt: transpose 64hw x 64c tile via LDS ----
    __shared__ float t[64][65];
    int tb = blk - 2592;                       // 0..1023
    int hwg = tb & 63;
    int cg  = (tb >> 6) & 3;
    int b   = tb >> 8;
    int hw0 = hwg * 64, c0 = cg * 64;
    int l = threadIdx.x & 63, q = threadIdx.x >> 6;
    const float* xb = x + ((size_t)(b * 256 + c0) << 12) + hw0;
#pragma unroll
    for (int i = 0; i < 16; ++i) {
      int cl = q * 16 + i;
      t[cl][l] = xb[((size_t)cl << 12) + l];
    }
    __syncthreads();
    __hip_bfloat16* xTb = xTh + (((size_t)b << 12) + hw0) * 256 + c0;
#pragma unroll
    for (int i = 0; i < 16; ++i) {
      int hwl = q * 16 + i;
      xTb[(size_t)hwl * 256 + l] = __float2bfloat16(t[l][hwl]);
    }
  }
}

// ---------------------------------------------------------------------------
// K23: FULLY fused (R20 body, best measured). 32 m x 256 o per block,
// grid 512 (2 blocks/CU), 256 thr (4 waves).
// Phase-1 kk-staged offset-conv GEMM -> sOM; phase-2 deformable gather +
// main GEMM (W-frags direct from L2; taps reg-staged; sV dbuf; 1 barrier/step).
// ---------------------------------------------------------------------------
__global__ __launch_bounds__(256, 2) void k23_fused(const __hip_bfloat16* __restrict__ xTh,
                                                    const __hip_bfloat16* __restrict__ Wt3,
                                                    const __hip_bfloat16* __restrict__ Wot3,
                                                    const float* __restrict__ boff,
                                                    float* __restrict__ out) {
  __shared__ __align__(16) __hip_bfloat16 sPatch[4][32 * 64];  // 16 KB (ph1: 4 cc sub-tiles; ph2: sPV dbuf)
  __shared__ float sOM[32][33];                                 // padded
  __shared__ float sw00[288], sw01[288], sw10[288], sw11[288];
  __shared__ int   so00[288], so01[288], so10[288], so11[288];

  __hip_bfloat16 (*sPV)[32 * 64] = sPatch;

  int bid = blockIdx.x;
  int tm = ((bid & 7) << 6) | (bid >> 3);   // chunked XCD swizzle, 0..511
  int tid = threadIdx.x;
  int wv = tid >> 6, lane = tid & 63;
  int lo = lane & 15, hi = lane >> 4;
  int b = tm >> 7;
  int m0 = tm * 32;

  // ===================== PHASE 1: om for own 32 rows (kk-staged) ==========
  {
    int wr = wv >> 1, wc = wv & 1;
    int prow = tid >> 3;
    int pkb  = (tid & 7) * 8;
    int pcolz = pkb ^ ((prow & 7) << 3);
    int m_s = m0 + prow;
    int hw_s = m_s & 4095, h_s = hw_s >> 6, w_s = hw_s & 63;

    f32x4 acc1 = {0.f, 0.f, 0.f, 0.f};
    const short8 zero8 = {0,0,0,0,0,0,0,0};

    for (int kk = 0; kk < KK9; ++kk) {
      int ky = kk / 3, kx = kk - ky * 3;
      int yy = h_s + ky - 1, xx = w_s + kx - 1;
      bool valid = ((unsigned)yy < 64u) && ((unsigned)xx < 64u);
      int cy = min(max(yy, 0), 63), cx = min(max(xx, 0), 63);
      const __hip_bfloat16* src = xTh + ((((size_t)b << 12) + cy * 64 + cx) << 8) + pkb;
#pragma unroll
      for (int cc = 0; cc < 4; ++cc) {
        short8 h8 = valid ? *(const short8*)(src + cc * 64) : zero8;
        *(short8*)&sPatch[cc][prow * 64 + pcolz] = h8;
      }
      __syncthreads();
#pragma unroll
      for (int cc = 0; cc < 4; ++cc) {
        int tk = kk * 4 + cc;
#pragma unroll
        for (int kc = 0; kc < 2; ++kc) {
          int cz = (kc * 32 + hi * 8) ^ ((lo & 7) << 3);
          short8 bfr = *(const short8*)&sPatch[cc][(wr * 16 + lo) * 64 + cz];
          short8 a = *(const short8*)((const char*)Wot3
                      + ((((size_t)tk * 2 + wc) * 2 + kc) << 10) + lane * 16);
          acc1 = __builtin_amdgcn_mfma_f32_16x16x32_bf16(a, bfr, acc1, 0, 0, 0);
        }
      }
      __syncthreads();
    }

    int oc0 = wc * 16 + hi * 4;
#pragma unroll
    for (int r = 0; r < 4; ++r) {
      float bias = (oc0 + r < 27) ? boff[oc0 + r] : 0.f;
      sOM[wr * 16 + lo][oc0 + r] = acc1[r] + bias;
    }
  }
  __syncthreads();

  // ============== PHASE 2 prologue A: gather params from sOM ==============
  for (int it = tid; it < 288; it += 256) {
    int kk = it >> 5, row = it & 31;
    int m = m0 + row;
    int hw = m & 4095, h = hw >> 6, w = hw & 63;
    float dy = sOM[row][2 * kk];
    float dx = sOM[row][2 * kk + 1];
    float mz = sOM[row][18 + kk];
    int ky = kk / 3, kx = kk - ky * 3;
    float py = dy + (float)(h - 1 + ky);
    float px = dx + (float)(w - 1 + kx);
    float y0f = floorf(py), x0f = floorf(px);
    float wy = py - y0f, wx = px - x0f;
    int y0 = (int)y0f, x0 = (int)x0f;
    bool vy0 = (unsigned)y0 < 64u, vy1 = (unsigned)(y0 + 1) < 64u;
    bool vx0 = (unsigned)x0 < 64u, vx1 = (unsigned)(x0 + 1) < 64u;
    int cy0 = min(max(y0, 0), 63), cy1 = min(max(y0 + 1, 0), 63);
    int cx0 = min(max(x0, 0), 63), cx1 = min(max(x0 + 1, 0), 63);
    float mask = 1.f / (1.f + __expf(-mz));
    sw00[it] = (vy0 && vx0) ? (1.f - wy) * (1.f - wx) * mask : 0.f;
    sw01[it] = (vy0 && vx1) ? (1.f - wy) * wx * mask : 0.f;
    sw10[it] = (vy1 && vx0) ? wy * (1.f - wx) * mask : 0.f;
    sw11[it] = (vy1 && vx1) ? wy * wx * mask : 0.f;
    so00[it] = cy0 * 64 + cx0;
    so01[it] = cy0 * 64 + cx1;
    so10[it] = cy1 * 64 + cx0;
    so11[it] = cy1 * 64 + cx1;
  }
  __syncthreads();

  // ===================== PHASE 2: main GEMM =====================
  const __hip_bfloat16* xb = xTh + ((size_t)b << 20);
  int vrow = tid >> 3;
  int chq  = tid & 7;
  int colz = (chq * 8) ^ ((vrow & 7) << 3);

  auto loadTaps = [&](int tkq, Taps& T) {
    int it = (tkq >> 2) * 32 + vrow;
    const __hip_bfloat16* base = xb + (tkq & 3) * 64 + chq * 8;
    T.t00 = *(const short8*)(base + (size_t)so00[it] * 256);
    T.t01 = *(const short8*)(base + (size_t)so01[it] * 256);
    T.t10 = *(const short8*)(base + (size_t)so10[it] * 256);
    T.t11 = *(const short8*)(base + (size_t)so11[it] * 256);
  };
  auto buildV = [&](int tkq, const Taps& T, int buf) {
    int it = (tkq >> 2) * 32 + vrow;
    float a00 = sw00[it], a01 = sw01[it], a10 = sw10[it], a11 = sw11[it];
    __hip_bfloat16 h8[8];
#pragma unroll
    for (int j = 0; j < 8; ++j) {
      float v = a00 * b2f(T.t00[j]) + a01 * b2f(T.t01[j])
              + a10 * b2f(T.t10[j]) + a11 * b2f(T.t11[j]);
      h8[j] = __float2bfloat16(v);
    }
    *(short8*)&sPV[buf][vrow * 64 + colz] = *(const short8*)h8;
  };
  auto loadW = [&](int tkq, short8 (&aw)[8]) {
#pragma unroll
    for (int fo = 0; fo < 4; ++fo)
#pragma unroll
      for (int kc = 0; kc < 2; ++kc)
        aw[fo * 2 + kc] = *(const short8*)((const char*)Wt3
                          + ((((size_t)tkq * 16 + (wv * 4 + fo)) * 2 + kc) << 10)
                          + lane * 16);
  };

  f32x4 zero4 = {0.f, 0.f, 0.f, 0.f};
  f32x4 acc[4][2];
#pragma unroll
  for (int fo = 0; fo < 4; ++fo)
#pragma unroll
    for (int fm = 0; fm < 2; ++fm) acc[fo][fm] = zero4;

  Taps TA, TB;
  short8 awA[8], awB[8];
  loadW(0, awA);
  loadTaps(0, TA);
  buildV(0, TA, 0);
  loadTaps(1, TB);
  asm volatile("s_waitcnt lgkmcnt(0)" ::: "memory");
  __builtin_amdgcn_s_barrier();

  auto body = [&](int tk, Taps& Tuse, Taps& Tload,
                  short8 (&awUse)[8], short8 (&awLoad)[8]) {
    int cb = tk & 1, nb = cb ^ 1;
    int tk1 = min(tk + 1, NKSTEP - 1), tk2 = min(tk + 2, NKSTEP - 1);
    loadW(tk1, awLoad);
    loadTaps(tk2, Tload);
    __builtin_amdgcn_sched_barrier(0);
    buildV(tk1, Tuse, nb);

    __builtin_amdgcn_s_setprio(1);
#pragma unroll
    for (int kc = 0; kc < 2; ++kc) {
      int cz = (kc * 32 + hi * 8) ^ ((lo & 7) << 3);
      short8 bv[2];
#pragma unroll
      for (int fm = 0; fm < 2; ++fm)
        bv[fm] = *(const short8*)&sPV[cb][(fm * 16 + lo) * 64 + cz];
#pragma unroll
      for (int fo = 0; fo < 4; ++fo)
#pragma unroll
        for (int fm = 0; fm < 2; ++fm)
          acc[fo][fm] = __builtin_amdgcn_mfma_f32_16x16x32_bf16(awUse[fo * 2 + kc], bv[fm], acc[fo][fm], 0, 0, 0);
    }
    __builtin_amdgcn_s_setprio(0);

    if (tk + 1 < NKSTEP) {
      asm volatile("s_waitcnt lgkmcnt(0)" ::: "memory");
      __builtin_amdgcn_s_barrier();
    }
  };

  for (int tkp = 0; tkp < NKSTEP; tkp += 2) {
    body(tkp,     TB, TA, awA, awB);
    body(tkp + 1, TA, TB, awB, awA);
  }

  // epilogue
  int hwbase = m0 & 4095;
#pragma unroll
  for (int fo = 0; fo < 4; ++fo) {
    int o = wv * 64 + fo * 16 + hi * 4;
#pragma unroll
    for (int fm = 0; fm < 2; ++fm) {
      int mloc = hwbase + fm * 16 + lo;
#pragma unroll
      for (int r = 0; r < 4; ++r)
        out[((size_t)(b * 256 + o + r)) * 4096 + mloc] = acc[fo][fm][r];
    }
  }
}

// ---------------------------------------------------------------------------
extern "C" void kernel_launch(void* const* d_in, const int* in_sizes, int n_in,
                              void* d_out, int out_size, void* d_ws, size_t ws_size,
                              hipStream_t stream) {
  (void)in_sizes; (void)n_in; (void)out_size; (void)ws_size;
  const float* x     = (const float*)d_in[0];
  const float* woff  = (const float*)d_in[1];
  const float* boff  = (const float*)d_in[2];
  const float* wconv = (const float*)d_in[3];
  char* ws = (char*)d_ws;
  __hip_bfloat16* xTh  = (__hip_bfloat16*)(ws + XT_OFF);
  __hip_bfloat16* Wt3  = (__hip_bfloat16*)(ws + WT_OFF);
  __hip_bfloat16* Wot3 = (__hip_bfloat16*)(ws + WOT_OFF);
  float* out = (float*)d_out;

  hipLaunchKernelGGL(k_prep,    dim3(3616), dim3(256), 0, stream, x, woff, wconv, Wt3, Wot3, xTh);
  hipLaunchKernelGGL(k23_fused, dim3(512),  dim3(256), 0, stream, xTh, Wt3, Wot3, boff, out);
}

// Round 23
// 61.681 us; speedup vs baseline: 1.1825x; 1.0015x over previous
//
#include <hip/hip_runtime.h>
#include <hip/hip_bf16.h>

// Problem constants
#define XH   64
#define XW   64
#define CIN  256
#define COUT 256
#define BATCH 4
#define KK9  9
#define M_TOT 16384      // BATCH*XH*XW
#define K_TOT 2304       // KK9*CIN
#define NKSTEP 36        // K_TOT/64

typedef __attribute__((ext_vector_type(8))) short short8;
typedef __attribute__((ext_vector_type(4))) float f32x4;

// Workspace layout (bytes)
#define XT_OFF   0
#define XT_BYTES (BATCH*4096*CIN*2)           // 8,388,608 (bf16)
#define WT_OFF   (XT_OFF + XT_BYTES)
#define WT_BYTES (COUT*K_TOT*2)               // 1,179,648  Wt3: A-fragment-ordered
#define WOT_OFF  (WT_OFF + WT_BYTES)
#define WOT_BYTES (36*2*2*64*8*2)             // 147,456    Wot3: A-fragment-ordered

__device__ __forceinline__ float b2f(short s) {
  union { float f; unsigned u; } x;
  x.u = ((unsigned)(unsigned short)s) << 16;
  return x.f;
}

struct Taps { short8 t00, t01, t10, t11; };

// ---------------------------------------------------------------------------
// K_PREP: merged k0 + k0b + kt (mutually independent; one dispatch removes
// two kernel-boundary gaps and runs them concurrently).
// blocks [0,2304)      : Wt3  (w_conv -> A-fragment order)
// blocks [2304,2592)   : Wot3 (w_off  -> A-fragment order, oc>=27 padded)
// blocks [2592,3616)   : xTh  (transpose x -> [b][hw][c] bf16)
// ---------------------------------------------------------------------------
__global__ __launch_bounds__(256) void k_prep(const float* __restrict__ x,
                                              const float* __restrict__ woff,
                                              const float* __restrict__ wconv,
                                              __hip_bfloat16* __restrict__ Wt3,
                                              __hip_bfloat16* __restrict__ Wot3,
                                              __hip_bfloat16* __restrict__ xTh) {
  int blk = blockIdx.x;
  if (blk < 2304) {
    // ---- k0: Wt3[tk(36)][og(16)][kc(2)][lane(64)][j(8)] ----
    int e = blk * 256 + threadIdx.x;           // < 589824
    int j3   = e & 7;
    int lane = (e >> 3) & 63;
    int kc   = (e >> 9) & 1;
    int og   = (e >> 10) & 15;
    int tk   = e >> 14;
    int o = og * 16 + (lane & 15);
    int k = tk * 64 + kc * 32 + ((lane >> 4) << 3) + j3;
    int kk = k >> 8, c = k & 255;
    float v = wconv[(o * CIN + c) * KK9 + kk];
    Wt3[e] = __float2bfloat16(v);
  } else if (blk < 2592) {
    // ---- k0b: Wot3[tk(36)][wc(2)][kc(2)][lane(64)][j(8)] ----
    int e = (blk - 2304) * 256 + threadIdx.x;  // < 73728
    int j3   = e & 7;
    int lane = (e >> 3) & 63;
    int kc   = (e >> 9) & 1;
    int wc   = (e >> 10) & 1;
    int tk   = e >> 11;
    int oc = wc * 16 + (lane & 15);
    int k = tk * 64 + kc * 32 + ((lane >> 4) << 3) + j3;
    int kk = k >> 8, c = k & 255;
    float v = (oc < 27) ? woff[((size_t)(oc * 256 + c)) * 9 + kk] : 0.f;
    Wot3[e] = __float2bfloat16(v);
  } else {
    // ---- kt: transpose 64hw x 64c tile via LDS ----
    __shared__ float t[64][65];
    int tb = blk - 2592;                       // 0..1023
    int hwg = tb & 63;
    int cg  = (tb >> 6) & 3;
    int b   = tb >> 8;
    int hw0 = hwg * 64, c0 = cg * 64;
    int l = threadIdx.x & 63, q = threadIdx.x >> 6;
    const float* xb = x + ((size_t)(b * 256 + c0) << 12) + hw0;
#pragma unroll
    for (int i = 0; i < 16; ++i) {
      int cl = q * 16 + i;
      t[cl][l] = xb[((size_t)cl << 12) + l];
    }
    __syncthreads();
    __hip_bfloat16* xTb = xTh + (((size_t)b << 12) + hw0) * 256 + c0;
#pragma unroll
    for (int i = 0; i < 16; ++i) {
      int hwl = q * 16 + i;
      xTb[(size_t)hwl * 256 + l] = __float2bfloat16(t[l][hwl]);
    }
  }
}

// ---------------------------------------------------------------------------
// K23: FULLY fused (best measured body). 32 m x 256 o per block, grid 512
// (2 blocks/CU), 256 thr (4 waves).
// Phase-1 kk-staged offset-conv GEMM -> sOM; phase-2 deformable gather +
// main GEMM (W-frags direct from L2; taps reg-staged; sV dbuf; 1 barrier/step).
// ---------------------------------------------------------------------------
__global__ __launch_bounds__(256, 2) void k23_fused(const __hip_bfloat16* __restrict__ xTh,
                                                    const __hip_bfloat16* __restrict__ Wt3,
                                                    const __hip_bfloat16* __restrict__ Wot3,
                                                    const float* __restrict__ boff,
                                                    float* __restrict__ out) {
  __shared__ __align__(16) __hip_bfloat16 sPatch[4][32 * 64];  // 16 KB (ph1: 4 cc sub-tiles; ph2: sPV dbuf)
  __shared__ float sOM[32][33];                                 // padded
  __shared__ float sw00[288], sw01[288], sw10[288], sw11[288];
  __shared__ int   so00[288], so01[288], so10[288], so11[288];

  __hip_bfloat16 (*sPV)[32 * 64] = sPatch;

  int bid = blockIdx.x;
  int tm = ((bid & 7) << 6) | (bid >> 3);   // chunked XCD swizzle, 0..511
  int tid = threadIdx.x;
  int wv = tid >> 6, lane = tid & 63;
  int lo = lane & 15, hi = lane >> 4;
  int b = tm >> 7;
  int m0 = tm * 32;

  // ===================== PHASE 1: om for own 32 rows (kk-staged) ==========
  {
    int wr = wv >> 1, wc = wv & 1;
    int prow = tid >> 3;
    int pkb  = (tid & 7) * 8;
    int pcolz = pkb ^ ((prow & 7) << 3);
    int m_s = m0 + prow;
    int hw_s = m_s & 4095, h_s = hw_s >> 6, w_s = hw_s & 63;

    f32x4 acc1 = {0.f, 0.f, 0.f, 0.f};
    const short8 zero8 = {0,0,0,0,0,0,0,0};

    for (int kk = 0; kk < KK9; ++kk) {
      int ky = kk / 3, kx = kk - ky * 3;
      int yy = h_s + ky - 1, xx = w_s + kx - 1;
      bool valid = ((unsigned)yy < 64u) && ((unsigned)xx < 64u);
      int cy = min(max(yy, 0), 63), cx = min(max(xx, 0), 63);
      const __hip_bfloat16* src = xTh + ((((size_t)b << 12) + cy * 64 + cx) << 8) + pkb;
#pragma unroll
      for (int cc = 0; cc < 4; ++cc) {
        short8 h8 = valid ? *(const short8*)(src + cc * 64) : zero8;
        *(short8*)&sPatch[cc][prow * 64 + pcolz] = h8;
      }
      __syncthreads();
#pragma unroll
      for (int cc = 0; cc < 4; ++cc) {
        int tk = kk * 4 + cc;
#pragma unroll
        for (int kc = 0; kc < 2; ++kc) {
          int cz = (kc * 32 + hi * 8) ^ ((lo & 7) << 3);
          short8 bfr = *(const short8*)&sPatch[cc][(wr * 16 + lo) * 64 + cz];
          short8 a = *(const short8*)((const char*)Wot3
                      + ((((size_t)tk * 2 + wc) * 2 + kc) << 10) + lane * 16);
          acc1 = __builtin_amdgcn_mfma_f32_16x16x32_bf16(a, bfr, acc1, 0, 0, 0);
        }
      }
      __syncthreads();
    }

    int oc0 = wc * 16 + hi * 4;
#pragma unroll
    for (int r = 0; r < 4; ++r) {
      float bias = (oc0 + r < 27) ? boff[oc0 + r] : 0.f;
      sOM[wr * 16 + lo][oc0 + r] = acc1[r] + bias;
    }
  }
  __syncthreads();

  // ============== PHASE 2 prologue A: gather params from sOM ==============
  for (int it = tid; it < 288; it += 256) {
    int kk = it >> 5, row = it & 31;
    int m = m0 + row;
    int hw = m & 4095, h = hw >> 6, w = hw & 63;
    float dy = sOM[row][2 * kk];
    float dx = sOM[row][2 * kk + 1];
    float mz = sOM[row][18 + kk];
    int ky = kk / 3, kx = kk - ky * 3;
    float py = dy + (float)(h - 1 + ky);
    float px = dx + (float)(w - 1 + kx);
    float y0f = floorf(py), x0f = floorf(px);
    float wy = py - y0f, wx = px - x0f;
    int y0 = (int)y0f, x0 = (int)x0f;
    bool vy0 = (unsigned)y0 < 64u, vy1 = (unsigned)(y0 + 1) < 64u;
    bool vx0 = (unsigned)x0 < 64u, vx1 = (unsigned)(x0 + 1) < 64u;
    int cy0 = min(max(y0, 0), 63), cy1 = min(max(y0 + 1, 0), 63);
    int cx0 = min(max(x0, 0), 63), cx1 = min(max(x0 + 1, 0), 63);
    float mask = 1.f / (1.f + __expf(-mz));
    sw00[it] = (vy0 && vx0) ? (1.f - wy) * (1.f - wx) * mask : 0.f;
    sw01[it] = (vy0 && vx1) ? (1.f - wy) * wx * mask : 0.f;
    sw10[it] = (vy1 && vx0) ? wy * (1.f - wx) * mask : 0.f;
    sw11[it] = (vy1 && vx1) ? wy * wx * mask : 0.f;
    so00[it] = cy0 * 64 + cx0;
    so01[it] = cy0 * 64 + cx1;
    so10[it] = cy1 * 64 + cx0;
    so11[it] = cy1 * 64 + cx1;
  }
  __syncthreads();

  // ===================== PHASE 2: main GEMM =====================
  const __hip_bfloat16* xb = xTh + ((size_t)b << 20);
  int vrow = tid >> 3;
  int chq  = tid & 7;
  int colz = (chq * 8) ^ ((vrow & 7) << 3);

  auto loadTaps = [&](int tkq, Taps& T) {
    int it = (tkq >> 2) * 32 + vrow;
    const __hip_bfloat16* base = xb + (tkq & 3) * 64 + chq * 8;
    T.t00 = *(const short8*)(base + (size_t)so00[it] * 256);
    T.t01 = *(const short8*)(base + (size_t)so01[it] * 256);
    T.t10 = *(const short8*)(base + (size_t)so10[it] * 256);
    T.t11 = *(const short8*)(base + (size_t)so11[it] * 256);
  };
  auto buildV = [&](int tkq, const Taps& T, int buf) {
    int it = (tkq >> 2) * 32 + vrow;
    float a00 = sw00[it], a01 = sw01[it], a10 = sw10[it], a11 = sw11[it];
    __hip_bfloat16 h8[8];
#pragma unroll
    for (int j = 0; j < 8; ++j) {
      float v = a00 * b2f(T.t00[j]) + a01 * b2f(T.t01[j])
              + a10 * b2f(T.t10[j]) + a11 * b2f(T.t11[j]);
      h8[j] = __float2bfloat16(v);
    }
    *(short8*)&sPV[buf][vrow * 64 + colz] = *(const short8*)h8;
  };
  auto loadW = [&](int tkq, short8 (&aw)[8]) {
#pragma unroll
    for (int fo = 0; fo < 4; ++fo)
#pragma unroll
      for (int kc = 0; kc < 2; ++kc)
        aw[fo * 2 + kc] = *(const short8*)((const char*)Wt3
                          + ((((size_t)tkq * 16 + (wv * 4 + fo)) * 2 + kc) << 10)
                          + lane * 16);
  };

  f32x4 zero4 = {0.f, 0.f, 0.f, 0.f};
  f32x4 acc[4][2];
#pragma unroll
  for (int fo = 0; fo < 4; ++fo)
#pragma unroll
    for (int fm = 0; fm < 2; ++fm) acc[fo][fm] = zero4;

  Taps TA, TB;
  short8 awA[8], awB[8];
  loadW(0, awA);
  loadTaps(0, TA);
  buildV(0, TA, 0);
  loadTaps(1, TB);
  asm volatile("s_waitcnt lgkmcnt(0)" ::: "memory");
  __builtin_amdgcn_s_barrier();

  auto body = [&](int tk, Taps& Tuse, Taps& Tload,
                  short8 (&awUse)[8], short8 (&awLoad)[8]) {
    int cb = tk & 1, nb = cb ^ 1;
    int tk1 = min(tk + 1, NKSTEP - 1), tk2 = min(tk + 2, NKSTEP - 1);
    loadW(tk1, awLoad);
    loadTaps(tk2, Tload);
    __builtin_amdgcn_sched_barrier(0);
    buildV(tk1, Tuse, nb);

    __builtin_amdgcn_s_setprio(1);
#pragma unroll
    for (int kc = 0; kc < 2; ++kc) {
      int cz = (kc * 32 + hi * 8) ^ ((lo & 7) << 3);
      short8 bv[2];
#pragma unroll
      for (int fm = 0; fm < 2; ++fm)
        bv[fm] = *(const short8*)&sPV[cb][(fm * 16 + lo) * 64 + cz];
#pragma unroll
      for (int fo = 0; fo < 4; ++fo)
#pragma unroll
        for (int fm = 0; fm < 2; ++fm)
          acc[fo][fm] = __builtin_amdgcn_mfma_f32_16x16x32_bf16(awUse[fo * 2 + kc], bv[fm], acc[fo][fm], 0, 0, 0);
    }
    __builtin_amdgcn_s_setprio(0);

    if (tk + 1 < NKSTEP) {
      asm volatile("s_waitcnt lgkmcnt(0)" ::: "memory");
      __builtin_amdgcn_s_barrier();
    }
  };

  for (int tkp = 0; tkp < NKSTEP; tkp += 2) {
    body(tkp,     TB, TA, awA, awB);
    body(tkp + 1, TA, TB, awB, awA);
  }

  // epilogue
  int hwbase = m0 & 4095;
#pragma unroll
  for (int fo = 0; fo < 4; ++fo) {
    int o = wv * 64 + fo * 16 + hi * 4;
#pragma unroll
    for (int fm = 0; fm < 2; ++fm) {
      int mloc = hwbase + fm * 16 + lo;
#pragma unroll
      for (int r = 0; r < 4; ++r)
        out[((size_t)(b * 256 + o + r)) * 4096 + mloc] = acc[fo][fm][r];
    }
  }
}

// ---------------------------------------------------------------------------
extern "C" void kernel_launch(void* const* d_in, const int* in_sizes, int n_in,
                              void* d_out, int out_size, void* d_ws, size_t ws_size,
                              hipStream_t stream) {
  (void)in_sizes; (void)n_in; (void)out_size; (void)ws_size;
  const float* x     = (const float*)d_in[0];
  const float* woff  = (const float*)d_in[1];
  const float* boff  = (const float*)d_in[2];
  const float* wconv = (const float*)d_in[3];
  char* ws = (char*)d_ws;
  __hip_bfloat16* xTh  = (__hip_bfloat16*)(ws + XT_OFF);
  __hip_bfloat16* Wt3  = (__hip_bfloat16*)(ws + WT_OFF);
  __hip_bfloat16* Wot3 = (__hip_bfloat16*)(ws + WOT_OFF);
  float* out = (float*)d_out;

  hipLaunchKernelGGL(k_prep,    dim3(3616), dim3(256), 0, stream, x, woff, wconv, Wt3, Wot3, xTh);
  hipLaunchKernelGGL(k23_fused, dim3(512),  dim3(256), 0, stream, xTh, Wt3, Wot3, boff, out);
}